// Round 16
// baseline (92.487 us; speedup 1.0000x reference)
//
#include <hip/hip_runtime.h>
#include <hip/hip_bf16.h>

#define S_LEN 2048
#define D_K   64
#define N_H   16
#define N_B   4
#define KVT   32                  // keys per (per-wave) tile
#define NBH   (N_B * N_H)
// ws: K_compact + V^T_compact (bf16, full-size padded) + cnt (+slack)
#define WS_NEED (2L * NBH * S_LEN * D_K * 2 + 4L * S_LEN * 4 + 16)

typedef __attribute__((ext_vector_type(8)))  short bf16x8;
typedef __attribute__((ext_vector_type(16))) float f32x16;
typedef unsigned int u32;
typedef __attribute__((ext_vector_type(4))) u32 u32x4;

__device__ inline short f2bfs(float x) {
    __hip_bfloat16 h = __float2bfloat16(x);
    return __builtin_bit_cast(short, h);
}

__device__ inline bf16x8 cvt8(const float* __restrict__ p) {
    float4 a = *(const float4*)p;
    float4 b = *(const float4*)(p + 4);
    bf16x8 f;
    f[0] = f2bfs(a.x); f[1] = f2bfs(a.y);
    f[2] = f2bfs(a.z); f[3] = f2bfs(a.w);
    f[4] = f2bfs(b.x); f[5] = f2bfs(b.y);
    f[6] = f2bfs(b.z); f[7] = f2bfs(b.w);
    return f;
}

__device__ inline bf16x8 cvt8s(const float* __restrict__ p, float s) {
    float4 a = *(const float4*)p;
    float4 b = *(const float4*)(p + 4);
    bf16x8 f;
    f[0] = f2bfs(a.x * s); f[1] = f2bfs(a.y * s);
    f[2] = f2bfs(a.z * s); f[3] = f2bfs(a.w * s);
    f[4] = f2bfs(b.x * s); f[5] = f2bfs(b.y * s);
    f[6] = f2bfs(b.z * s); f[7] = f2bfs(b.w * s);
    return f;
}

// legacy-fallback V^T swizzle
__device__ inline int vswz(int d) { return ((d & 7) ^ ((d >> 3) & 7)) << 4; }

// ---------------- fused pass: mask scan + gather + convert ----------------
__global__ __launch_bounds__(256)
void gather_cvt(const float* __restrict__ k, const float* __restrict__ v,
                const int* __restrict__ mask, const int dummy,
                short* __restrict__ kc, short* __restrict__ vt,
                int* __restrict__ cnt) {
    const int bid = blockIdx.x, bh = bid >> 5, i0 = (bid & 31) * 64;
    const int b = bh >> 4;
    const int t = threadIdx.x;

    __shared__ __align__(16) short tile_[64][72];
    __shared__ int idx_s[64];
    __shared__ int m_s;

    if (t < 64) {
        const int lane = t;
        const int* mb = mask + b * S_LEN;
        int base = 0;
#pragma unroll 4
        for (int j0 = 0; j0 < S_LEN; j0 += 64) {
            int mv = mb[j0 + lane];
            unsigned long long ball = __ballot(mv != 0);
            int pos = base + __popcll(ball & ((1ull << lane) - 1ull));
            if (mv && pos >= i0 && pos < i0 + 64) idx_s[pos - i0] = j0 + lane;
            base += __popcll(ball);
        }
        if (lane == 0) m_s = base;
    }
    __syncthreads();
    const int m = m_s;
    if (t == 0 && i0 == 0) cnt[b] = m;
    if (i0 >= ((m + 63) & ~63)) return;

    const int r = t >> 2, c0 = (t & 3) * 16;
    const int i = i0 + r;

    bf16x8 fv0, fv1, fk0, fk1;
    if (i < m) {
        const int src = idx_s[r];
        const float* kp = k + ((long)bh * S_LEN + src) * D_K + c0;
        const float* vp = v + ((long)bh * S_LEN + src) * D_K + c0;
        fk0 = cvt8(kp); fk1 = cvt8(kp + 8);
        fv0 = cvt8(vp); fv1 = cvt8(vp + 8);
    } else {
#pragma unroll
        for (int j = 0; j < 8; ++j) { fk0[j] = 0; fk1[j] = 0; fv0[j] = 0; fv1[j] = 0; }
    }
    short* kdst = kc + ((long)bh * S_LEN + i) * D_K + c0;
    *(bf16x8*)kdst       = fk0;
    *(bf16x8*)(kdst + 8) = fk1;
    *(bf16x8*)&tile_[r][c0]     = fv0;
    *(bf16x8*)&tile_[r][c0 + 8] = fv1;
    __syncthreads();
    const int dd = t >> 2, k0 = (t & 3) * 16;
    bf16x8 h0, h1;
#pragma unroll
    for (int j = 0; j < 8; ++j) {
        h0[j] = tile_[k0 + j][dd];
        h1[j] = tile_[k0 + 8 + j][dd];
    }
    short* dst = vt + ((long)bh * D_K + dd) * S_LEN + i0 + k0;
    *(bf16x8*)dst       = h0;
    *(bf16x8*)(dst + 8) = h1;
}

// ---------------- main attention kernel: per-wave staging + T14 split ----
// 4 INDEPENDENT waves / 256-thread block, zero block barriers. Each wave:
// 32 q-rows, private 8 KB LDS (K 4KB + V^T 4KB, KVT=32, single buffer).
// T14 async-STAGE: regs hold tile t+1 (global loads issued one full tile
// earlier -> L2 latency hidden under compute); after PV(t) retires its LDS
// reads, regs are ds_written and loads for t+2 are issued. All ordering is
// intra-wave; the compiler inserts the needed waitcnts.
__global__ __launch_bounds__(256)
void attn_fwd(const float* __restrict__ q, const short* __restrict__ kbf,
              const short* __restrict__ vtb, const int* __restrict__ cnt,
              float* __restrict__ out) {
    // XCD-aware bijective swizzle (1024 = 8*128): 8 bh per XCD
    const int id      = blockIdx.x;
    const int logical = (id & 7) * 128 + (id >> 3);
    const int bh      = logical >> 4;          // 0..63
    const int qb4     = logical & 15;          // 0..15 (4 q-waves each)
    const int b       = bh >> 4;
    const int t       = threadIdx.x;
    const int lane    = t & 63;
    const int wq      = t >> 6;                // independent wave 0..3
    const int hb      = lane >> 5;
    const int ql      = lane & 31;

    const int m   = cnt[b];
    const int NTr = (m + KVT - 1) >> 5;

    __shared__ __align__(16) char lds[4][8192];  // per-wave private region
    char* kl = &lds[wq][0];       // K tile:  [row 0..31][chunk 0..7], 128B rows
    char* vl = &lds[wq][4096];    // V^T tile: [d 0..63][chunk 0..3],  64B rows

    const float scale2 = 0.125f * 1.44269504f;   // 1/sqrt(64)*log2(e)
    const long  baseq  = (long)bh * S_LEN * D_K;
    const int   qrow0  = qb4 * 128 + wq * 32;

    // ---- Q fragments (pre-scaled): B-layout col=ql, k = kd*16 + hb*8 + j ----
    bf16x8 qf[4];
    {
        const float* qp = q + baseq + (long)(qrow0 + ql) * D_K + hb * 8;
#pragma unroll
        for (int kd = 0; kd < 4; ++kd) qf[kd] = cvt8s(qp + kd * 16, scale2);
    }

    // ---- staging sources (pre-swizzled so LDS-linear dest == swizzled) ----
    const int krow_ = lane >> 3, kchk_ = lane & 7;
    const short* ks0 = kbf + baseq + (long)krow_ * D_K
                       + ((kchk_ ^ (krow_ & 7)) * 8);
    const int vd_ = lane >> 2, vc_ = lane & 3;
    const short* vs0 = vtb + ((long)bh * D_K + vd_) * S_LEN
                       + ((vc_ ^ ((vd_ >> 1) & 3)) * 8);

    // ---- T14 staging registers (one tile in flight) ----
    bf16x8 kreg[4], vreg[4];
    auto LOADR = [&](int tile) {               // issue 8 global 16B loads -> regs
        const short* kp = ks0 + (long)tile * (KVT * D_K);
        const short* vp = vs0 + tile * KVT;
#pragma unroll
        for (int i = 0; i < 4; ++i)
            kreg[i] = *(const bf16x8*)(kp + i * (8 * D_K));
#pragma unroll
        for (int i = 0; i < 4; ++i)
            vreg[i] = *(const bf16x8*)(vp + (long)i * 16 * S_LEN);
    };
    auto WRITEL = [&]() {                      // regs -> private LDS (linear)
#pragma unroll
        for (int i = 0; i < 4; ++i)
            *(bf16x8*)(kl + i * 1024 + lane * 16) = kreg[i];
#pragma unroll
        for (int i = 0; i < 4; ++i)
            *(bf16x8*)(vl + i * 1024 + lane * 16) = vreg[i];
    };

    f32x16 o0, o1;
#pragma unroll
    for (int r = 0; r < 16; ++r) { o0[r] = 0.f; o1[r] = 0.f; }
    float lpart = 0.f;

    f32x16 ZEROV;
#pragma unroll
    for (int r = 0; r < 16; ++r) ZEROV[r] = 0.f;

    // ---- prologue: tile 0 -> LDS; tile 1 loads in flight ----
    LOADR(0);
    WRITEL();
    if (NTr > 1) LOADR(1);

    for (int tt = 0; tt < NTr; ++tt) {
        // ---- QK: st = K_tile . Q^T (32 keys, 4-MFMA chain) ----
        f32x16 st;
        {
            const int sz = (ql & 7) << 4;
            const int rb = ql * 128;
            f32x16 a;
            __builtin_amdgcn_s_setprio(1);
            {
                bf16x8 kf = *(const bf16x8*)(kl + ((rb + (hb * 8) * 2) ^ sz));
                if (tt + 1 < NTr) {
                    a = __builtin_amdgcn_mfma_f32_32x32x16_bf16(kf, qf[0], ZEROV, 0, 0, 0);
                } else {
                    f32x16 c0;
                    int keyb = tt * KVT + 4 * hb;
#pragma unroll
                    for (int r = 0; r < 16; ++r) {
                        int key = keyb + (r & 3) + 8 * (r >> 2);
                        c0[r] = (key < m) ? 0.f : -1e9f;
                    }
                    a = __builtin_amdgcn_mfma_f32_32x32x16_bf16(kf, qf[0], c0, 0, 0, 0);
                }
            }
#pragma unroll
            for (int kd = 1; kd < 4; ++kd) {
                bf16x8 kf = *(const bf16x8*)(kl + ((rb + (kd * 16 + hb * 8) * 2) ^ sz));
                a = __builtin_amdgcn_mfma_f32_32x32x16_bf16(kf, qf[kd], a, 0, 0, 0);
            }
            __builtin_amdgcn_s_setprio(0);
            st = a;
        }

        // ---- softmax: P = exp2(st), pack bf16 pairs ----
        u32 w[8];
        {
            float rs0 = 0.f, rs1 = 0.f;
#pragma unroll
            for (int mm = 0; mm < 8; ++mm) {
                float p0 = __builtin_amdgcn_exp2f(st[2 * mm]);
                float p1 = __builtin_amdgcn_exp2f(st[2 * mm + 1]);
                rs0 += p0; rs1 += p1;
                u32 r;
                asm("v_cvt_pk_bf16_f32 %0, %1, %2" : "=v"(r) : "v"(p0), "v"(p1));
                w[mm] = r;
            }
            lpart += rs0 + rs1;
        }

        // ---- PV: A-frag via permlane32_swap, B = V^T LDS reads ----
#pragma unroll
        for (int kbi = 0; kbi < 2; ++kbi) {
            int a2 = kbi * 4;
            u32 x0 = w[a2 + 0], y0 = w[a2 + 2];
            u32 x1 = w[a2 + 1], y1 = w[a2 + 3];
            asm("v_permlane32_swap_b32 %0, %1" : "+v"(x0), "+v"(y0));
            asm("v_permlane32_swap_b32 %0, %1" : "+v"(x1), "+v"(y1));
            u32x4 av = {x0, x1, y0, y1};       // j01, j23, j45, j67
            bf16x8 pa = __builtin_bit_cast(bf16x8, av);
            __builtin_amdgcn_s_setprio(1);
#pragma unroll
            for (int dn = 0; dn < 2; ++dn) {
                int d = dn * 32 + ql;
                int byte = d * 64 + (((kbi * 16 + hb * 8) * 2) ^ (((ql >> 1) & 3) << 4));
                bf16x8 vf = *(const bf16x8*)(vl + byte);
                if (dn == 0)
                    o0 = __builtin_amdgcn_mfma_f32_32x32x16_bf16(pa, vf, o0, 0, 0, 0);
                else
                    o1 = __builtin_amdgcn_mfma_f32_32x32x16_bf16(pa, vf, o1, 0, 0, 0);
            }
            __builtin_amdgcn_s_setprio(0);
        }

        // ---- T14 write-late: tile tt+1 regs -> LDS; issue loads for tt+2 ----
        if (tt + 1 < NTr) {
            WRITEL();                    // compiler orders vs PV's ds_reads
            if (tt + 2 < NTr) LOADR(tt + 2);
        }
    }

    // ---- epilogue: lrun = own + partner halves; out = o / lrun ----
    float lrun = lpart + __shfl_xor(lpart, 32, 64);
    float rl = 1.0f / lrun;
#pragma unroll
    for (int r = 0; r < 16; ++r) {
        int   cr  = (r & 3) + 8 * (r >> 2) + 4 * hb;
        float rlr = __shfl(rl, cr, 64);
        long  rowb = baseq + (long)(qrow0 + cr) * D_K;
        out[rowb + ql]      = o0[r] * rlr;
        out[rowb + 32 + ql] = o1[r] * rlr;
    }
}

// ---------------- fallback (no compaction) if ws too small ----------------
__global__ __launch_bounds__(256)
void attn_fwd_legacy(const float* __restrict__ q, const float* __restrict__ k,
                     const float* __restrict__ v, const int* __restrict__ mask,
                     float* __restrict__ out) {
    const int id      = blockIdx.x;
    const int logical = (id & 7) * 128 + (id >> 3);
    const int bh      = logical >> 4;
    const int qblk    = logical & 15;
    const int b       = bh >> 4;
    const int t       = threadIdx.x;
    const int lane    = t & 63;
    const int wq      = t >> 6;
    const int hb      = lane >> 5;
    const int ql      = lane & 31;

    __shared__ __align__(16) short kbuf[64 * D_K];
    __shared__ __align__(16) short vtbuf[D_K * 64];
    __shared__ float mbias[S_LEN];

    const float scale2 = 0.125f * 1.44269504f;
    const long  base   = (long)bh * S_LEN * D_K;
    const int   qrow0  = qblk * 128 + wq * 32;

    {
        const int* mb = mask + b * S_LEN;
        for (int i = t; i < S_LEN; i += 256)
            mbias[i] = mb[i] ? 0.f : -1.442695e9f;
    }

    bf16x8 qf[4];
    {
        const float* qp = q + base + (long)(qrow0 + ql) * D_K + hb * 8;
#pragma unroll
        for (int kd = 0; kd < 4; ++kd) qf[kd] = cvt8s(qp + kd * 16, 1.0f);
    }

    f32x16 o0, o1;
#pragma unroll
    for (int r = 0; r < 16; ++r) { o0[r] = 0.f; o1[r] = 0.f; }
    float mrun = -1e30f, lrun = 0.f;

    const int srow = t >> 3;
    const int scol = t & 7;
    float4 kr[2][2], vr[2][2];

    auto LOADT = [&](int kv0) {
#pragma unroll
        for (int u2 = 0; u2 < 2; ++u2) {
            int row = srow + u2 * 32;
            const float* kp = k + base + (long)(kv0 + row) * D_K + scol * 8;
            const float* vp = v + base + (long)(kv0 + row) * D_K + scol * 8;
            kr[u2][0] = *(const float4*)kp; kr[u2][1] = *(const float4*)(kp + 4);
            vr[u2][0] = *(const float4*)vp; vr[u2][1] = *(const float4*)(vp + 4);
        }
    };

    LOADT(0);

    for (int tt = 0; tt < S_LEN / 64; ++tt) {
        const int kv0 = tt * 64;
        __syncthreads();
#pragma unroll
        for (int u2 = 0; u2 < 2; ++u2) {
            int row = srow + u2 * 32;
            bf16x8 fk, fv;
#pragma unroll
            for (int j = 0; j < 4; ++j) {
                fk[j]     = f2bfs(((const float*)&kr[u2][0])[j]);
                fk[j + 4] = f2bfs(((const float*)&kr[u2][1])[j]);
                fv[j]     = f2bfs(((const float*)&vr[u2][0])[j]);
                fv[j + 4] = f2bfs(((const float*)&vr[u2][1])[j]);
            }
            int kbyte = (row * 128 + scol * 16) ^ ((row & 7) << 4);
            *(bf16x8*)((char*)kbuf + kbyte) = fk;
#pragma unroll
            for (int j = 0; j < 8; ++j) {
                int d = scol * 8 + j;
                *(short*)((char*)vtbuf + ((d * 128 + row * 2) ^ vswz(d))) = fv[j];
            }
        }
        if (tt + 1 < S_LEN / 64) LOADT(kv0 + 64);
        __syncthreads();

        f32x16 stl[2];
#pragma unroll
        for (int kb32 = 0; kb32 < 2; ++kb32) {
            f32x16 acc;
#pragma unroll
            for (int r = 0; r < 16; ++r) acc[r] = 0.f;
            int krow = kb32 * 32 + ql;
            int rb = krow * 128, sz = (krow & 7) << 4;
#pragma unroll
            for (int kd = 0; kd < 4; ++kd) {
                bf16x8 kf = *(const bf16x8*)((const char*)kbuf + ((rb + (kd * 16 + hb * 8) * 2) ^ sz));
                acc = __builtin_amdgcn_mfma_f32_32x32x16_bf16(kf, qf[kd], acc, 0, 0, 0);
            }
            stl[kb32] = acc;
        }
#pragma unroll
        for (int kb32 = 0; kb32 < 2; ++kb32)
#pragma unroll
            for (int r = 0; r < 16; ++r) {
                int key = kv0 + kb32 * 32 + (r & 3) + 8 * (r >> 2) + 4 * hb;
                stl[kb32][r] = fmaf(stl[kb32][r], scale2, mbias[key]);
            }

        float m8[8];
#pragma unroll
        for (int i = 0; i < 8; ++i)
            m8[i] = fmaxf(fmaxf(stl[0][i], stl[0][i + 8]),
                          fmaxf(stl[1][i], stl[1][i + 8]));
        float tmax = fmaxf(fmaxf(fmaxf(m8[0], m8[1]), fmaxf(m8[2], m8[3])),
                           fmaxf(fmaxf(m8[4], m8[5]), fmaxf(m8[6], m8[7])));
        tmax = fmaxf(tmax, __shfl_xor(tmax, 32, 64));

        if (__any(tmax > mrun + 10.0f)) {
            float mnew = fmaxf(mrun, tmax);
            float al   = __builtin_amdgcn_exp2f(mrun - mnew);
            mrun = mnew;
            lrun *= al;
#pragma unroll
            for (int r = 0; r < 16; ++r) {
                float ar = __shfl(al, (r & 3) + 8 * (r >> 2) + 4 * hb, 64);
                o0[r] *= ar; o1[r] *= ar;
            }
        }

        u32 w[2][8];
        float rs = 0.f;
#pragma unroll
        for (int kb32 = 0; kb32 < 2; ++kb32)
#pragma unroll
            for (int mm = 0; mm < 8; ++mm) {
                float p0 = __builtin_amdgcn_exp2f(stl[kb32][2 * mm]     - mrun);
                float p1 = __builtin_amdgcn_exp2f(stl[kb32][2 * mm + 1] - mrun);
                rs += p0 + p1;
                w[kb32][mm] = (u32)(unsigned short)f2bfs(p0) |
                              ((u32)(unsigned short)f2bfs(p1) << 16);
            }
        rs += __shfl_xor(rs, 32, 64);
        lrun += rs;

#pragma unroll
        for (int kbi = 0; kbi < 4; ++kbi) {
            int c = kbi >> 1, a2 = (kbi & 1) * 4;
            u32 x0 = w[c][a2 + 0], y0 = w[c][a2 + 2];
            u32 x1 = w[c][a2 + 1], y1 = w[c][a2 + 3];
            asm("v_permlane32_swap_b32 %0, %1" : "+v"(x0), "+v"(y0));
            asm("v_permlane32_swap_b32 %0, %1" : "+v"(x1), "+v"(y1));
            u32x4 av = {x0, x1, y0, y1};
            bf16x8 pa = __builtin_bit_cast(bf16x8, av);
#pragma unroll
            for (int dn = 0; dn < 2; ++dn) {
                int d = dn * 32 + ql;
                bf16x8 vf = *(const bf16x8*)((const char*)vtbuf +
                              ((d * 128 + (kbi * 16 + hb * 8) * 2) ^ vswz(d)));
                if (dn == 0)
                    o0 = __builtin_amdgcn_mfma_f32_32x32x16_bf16(pa, vf, o0, 0, 0, 0);
                else
                    o1 = __builtin_amdgcn_mfma_f32_32x32x16_bf16(pa, vf, o1, 0, 0, 0);
            }
        }
    }

    float rl = 1.0f / lrun;
#pragma unroll
    for (int r = 0; r < 16; ++r) {
        int   cr  = (r & 3) + 8 * (r >> 2) + 4 * hb;
        float rlr = __shfl(rl, cr, 64);
        long  rowb = base + (long)(qrow0 + cr) * D_K;
        out[rowb + ql]      = o0[r] * rlr;
        out[rowb + 32 + ql] = o1[r] * rlr;
    }
}

extern "C" void kernel_launch(void* const* d_in, const int* in_sizes, int n_in,
                              void* d_out, int out_size, void* d_ws, size_t ws_size,
                              hipStream_t stream) {
    const float* q    = (const float*)d_in[0];
    const float* k    = (const float*)d_in[1];
    const float* v    = (const float*)d_in[2];
    const int*   mask = (const int*)d_in[3];
    float*       out  = (float*)d_out;

    if (ws_size >= (size_t)WS_NEED) {
        short* kc  = (short*)d_ws;
        short* vt  = kc + (long)NBH * S_LEN * D_K;
        int*   cnt = (int*)(vt + (long)NBH * S_LEN * D_K);
        gather_cvt<<<dim3(NBH * (S_LEN / 64)), 256, 0, stream>>>(k, v, mask, 0, kc, vt, cnt);
        // 1024 blocks x 4 independent waves (64 q-waves per bh)
        attn_fwd<<<dim3((S_LEN / 32) * NBH / 4), 256, 0, stream>>>(q, kc, vt, cnt, out);
    } else {
        attn_fwd_legacy<<<dim3((S_LEN / 128) * NBH), 256, 0, stream>>>(q, k, v, mask, out);
    }
}

// Round 17
// 77.575 us; speedup vs baseline: 1.1922x; 1.1922x over previous
//
#include <hip/hip_runtime.h>
#include <hip/hip_bf16.h>

#define S_LEN 2048
#define D_K   64
#define N_H   16
#define N_B   4
#define KVB   64
#define QPB   256                 // q-rows per block (8 waves x 32)
#define NQB   (S_LEN / QPB)       // 8
#define NBH   (N_B * N_H)
// ws: K_compact + V^T_compact (bf16, full-size padded) + cnt (+slack)
#define WS_NEED (2L * NBH * S_LEN * D_K * 2 + 4L * S_LEN * 4 + 16)

typedef __attribute__((ext_vector_type(8)))  short bf16x8;
typedef __attribute__((ext_vector_type(16))) float f32x16;
typedef unsigned int u32;
typedef __attribute__((ext_vector_type(4))) u32 u32x4;

__device__ inline short f2bfs(float x) {
    __hip_bfloat16 h = __float2bfloat16(x);
    return __builtin_bit_cast(short, h);
}

__device__ inline bf16x8 cvt8(const float* __restrict__ p) {
    float4 a = *(const float4*)p;
    float4 b = *(const float4*)(p + 4);
    bf16x8 f;
    f[0] = f2bfs(a.x); f[1] = f2bfs(a.y);
    f[2] = f2bfs(a.z); f[3] = f2bfs(a.w);
    f[4] = f2bfs(b.x); f[5] = f2bfs(b.y);
    f[6] = f2bfs(b.z); f[7] = f2bfs(b.w);
    return f;
}

__device__ inline bf16x8 cvt8s(const float* __restrict__ p, float s) {
    float4 a = *(const float4*)p;
    float4 b = *(const float4*)(p + 4);
    bf16x8 f;
    f[0] = f2bfs(a.x * s); f[1] = f2bfs(a.y * s);
    f[2] = f2bfs(a.z * s); f[3] = f2bfs(a.w * s);
    f[4] = f2bfs(b.x * s); f[5] = f2bfs(b.y * s);
    f[6] = f2bfs(b.z * s); f[7] = f2bfs(b.w * s);
    return f;
}

// V^T swizzle: spreads row-d b128 reads across banks
__device__ inline int vswz(int d) { return ((d & 7) ^ ((d >> 3) & 7)) << 4; }

__device__ inline void gld16(const void* g, void* l) {
    __builtin_amdgcn_global_load_lds(
        (const __attribute__((address_space(1))) void*)g,
        (__attribute__((address_space(3))) void*)l, 16, 0, 0);
}

// ---------------- fused pass: mask scan + gather + convert ----------------
// Each block: wave 0 recomputes the stable compaction scan of mask[b]
// (32 ballot rounds over L2-broadcast data) into LDS idx_s[64] + m; then all
// 4 waves gather K rows -> bf16 compact [bh][i][d] and V rows -> bf16
// transposed compact [bh][d][i], zero-padding the last partial tile.
__global__ __launch_bounds__(256)
void gather_cvt(const float* __restrict__ k, const float* __restrict__ v,
                const int* __restrict__ mask, const int dummy,
                short* __restrict__ kc, short* __restrict__ vt,
                int* __restrict__ cnt) {
    const int bid = blockIdx.x, bh = bid >> 5, i0 = (bid & 31) * 64;
    const int b = bh >> 4;
    const int t = threadIdx.x;

    __shared__ __align__(16) short tile_[64][72];
    __shared__ int idx_s[64];
    __shared__ int m_s;

    // ---- wave 0: stable compaction scan, keep positions [i0, i0+64) ----
    if (t < 64) {
        const int lane = t;
        const int* mb = mask + b * S_LEN;
        int base = 0;
#pragma unroll 4
        for (int j0 = 0; j0 < S_LEN; j0 += 64) {
            int mv = mb[j0 + lane];
            unsigned long long ball = __ballot(mv != 0);
            int pos = base + __popcll(ball & ((1ull << lane) - 1ull));
            if (mv && pos >= i0 && pos < i0 + 64) idx_s[pos - i0] = j0 + lane;
            base += __popcll(ball);
        }
        if (lane == 0) m_s = base;
    }
    __syncthreads();
    const int m = m_s;
    if (t == 0 && i0 == 0) cnt[b] = m;
    if (i0 >= ((m + 63) & ~63)) return;      // block-uniform: beyond padded region

    const int r = t >> 2, c0 = (t & 3) * 16;
    const int i = i0 + r;

    bf16x8 fv0, fv1, fk0, fk1;
    if (i < m) {
        const int src = idx_s[r];
        const float* kp = k + ((long)bh * S_LEN + src) * D_K + c0;
        const float* vp = v + ((long)bh * S_LEN + src) * D_K + c0;
        fk0 = cvt8(kp); fk1 = cvt8(kp + 8);
        fv0 = cvt8(vp); fv1 = cvt8(vp + 8);
    } else {
#pragma unroll
        for (int j = 0; j < 8; ++j) { fk0[j] = 0; fk1[j] = 0; fv0[j] = 0; fv1[j] = 0; }
    }
    // K compact (row-major [bh][i][d])
    short* kdst = kc + ((long)bh * S_LEN + i) * D_K + c0;
    *(bf16x8*)kdst       = fk0;
    *(bf16x8*)(kdst + 8) = fk1;
    // V transpose via padded LDS -> [bh][d][i]
    *(bf16x8*)&tile_[r][c0]     = fv0;
    *(bf16x8*)&tile_[r][c0 + 8] = fv1;
    __syncthreads();
    const int dd = t >> 2, k0 = (t & 3) * 16;
    bf16x8 h0, h1;
#pragma unroll
    for (int j = 0; j < 8; ++j) {
        h0[j] = tile_[k0 + j][dd];
        h1[j] = tile_[k0 + 8 + j][dd];
    }
    short* dst = vt + ((long)bh * D_K + dd) * S_LEN + i0 + k0;
    *(bf16x8*)dst       = h0;
    *(bf16x8*)(dst + 8) = h1;
}

// ---------------- main attention kernel (compacted bf16 K / V^T) ----------------
// 8 waves/block (512 thr), 256 q-rows/block. 2-tile spans between barriers:
// K ring x5, V ring x4; per span stage {K t+4, K t+5, V t+2, V t+3}, then
// SM(t0) QK(t0+1) PV(t0) SM(t1) QK(t1+1) PV(t1), one __syncthreads.
// lrun cross-half reduce deferred to epilogue (one shfl_xor total).
__global__ __launch_bounds__(512)
void attn_fwd(const float* __restrict__ q, const short* __restrict__ kbf,
              const short* __restrict__ vtb, const int* __restrict__ cnt,
              float* __restrict__ out) {
    // XCD-aware bijective swizzle (512 = 8*64): 8 bh per XCD, qblk fastest
    const int id      = blockIdx.x;
    const int logical = (id & 7) * 64 + (id >> 3);
    const int bh      = logical >> 3;
    const int qblk    = logical & 7;
    const int b       = bh >> 4;
    const int t       = threadIdx.x;
    const int lane    = t & 63;
    const int wq      = t >> 6;     // wave 0..7
    const int hb      = lane >> 5;
    const int ql      = lane & 31;

    const int m   = cnt[b];                   // unmasked key count for this batch
    const int NTr = (m + 63) >> 6;            // tiles to process

    // LDS = 40K (K ring x5) + 32K (V ring x4) = 72 KB -> 2 blocks/CU (144K)
    __shared__ __align__(16) short kbuf[5][KVB * D_K];   // [key][d], XOR (row&7)<<4
    __shared__ __align__(16) short vbuf[4][D_K * KVB];   // [d][key], XOR vswz(d)

    const float scale2 = 0.125f * 1.44269504f;           // 1/sqrt(64)*log2(e)
    const long  baseq  = (long)bh * S_LEN * D_K;
    const int   qrow0  = qblk * QPB + wq * 32;

    // ---- Q fragments (pre-scaled): B-layout col=ql, k = kd*16 + hb*8 + j ----
    bf16x8 qf[4];
    {
        const float* qp = q + baseq + (long)(qrow0 + ql) * D_K + hb * 8;
#pragma unroll
        for (int kd = 0; kd < 4; ++kd) qf[kd] = cvt8s(qp + kd * 16, scale2);
    }

    // ---- staging bases: wave wq stages rows [8wq, 8wq+8); 1 K + 1 V load/tile ----
    const int lrow = lane >> 3, lchk = lane & 7;
    const int rA = wq * 8 + lrow;             // 0..63
    const short* ksA = kbf + baseq + (long)rA * D_K + ((lchk ^ (rA & 7)) * 8);
    const short* vsA = vtb + ((long)bh * D_K + rA) * S_LEN
                       + ((lchk ^ ((rA & 7) ^ ((rA >> 3) & 7))) * 8);

    auto STAGE_K = [&](int i) {              // K tile i -> slot i%5
        gld16(ksA + (long)i * (KVB * D_K),
              (char*)kbuf + (i % 5) * (KVB * D_K * 2) + (wq * 8) * 128);
    };
    auto STAGE_V = [&](int i) {              // V tile i -> slot i%4
        gld16(vsA + (long)i * KVB,
              (char*)vbuf + (i % 4) * (D_K * KVB * 2) + (wq * 8) * 128);
    };

    f32x16 o0, o1;
#pragma unroll
    for (int r = 0; r < 16; ++r) { o0[r] = 0.f; o1[r] = 0.f; }
    float lpart = 0.f;   // per-lane partial of lrun; cross-half reduce deferred

    // loop-invariant zero C-operand (hoisted acc-init: kd=0 MFMA consumes it)
    f32x16 ZEROV;
#pragma unroll
    for (int r = 0; r < 16; ++r) ZEROV[r] = 0.f;

    // st = logits of the CURRENT tile (computed one tile-phase ahead)
    f32x16 st0, st1;

    // QK for tile at kv0 from K slot sel; dual acc chains; kd=0 peeled so
    // C-in is ZEROV (common path) or mask vector (last tile only).
    auto QK = [&](int kv0, int sel, bool lastt) {
        const char* kbp = (const char*)kbuf + sel * (KVB * D_K * 2);
        int rb0 = (ql) * 128,      sz0 = (ql & 7) << 4;
        int rb1 = (32 + ql) * 128;
        f32x16 a0, a1;
        __builtin_amdgcn_s_setprio(1);
        {
            int co = (hb * 8) * 2;
            bf16x8 kf0 = *(const bf16x8*)(kbp + ((rb0 + co) ^ sz0));
            bf16x8 kf1 = *(const bf16x8*)(kbp + ((rb1 + co) ^ sz0));
            if (!lastt) {
                a0 = __builtin_amdgcn_mfma_f32_32x32x16_bf16(kf0, qf[0], ZEROV, 0, 0, 0);
                a1 = __builtin_amdgcn_mfma_f32_32x32x16_bf16(kf1, qf[0], ZEROV, 0, 0, 0);
            } else {
                f32x16 c0, c1;
                int keyb = kv0 + 4 * hb;
#pragma unroll
                for (int r = 0; r < 16; ++r) {
                    int key = keyb + (r & 3) + 8 * (r >> 2);
                    c0[r] = (key < m)      ? 0.f : -1e9f;
                    c1[r] = (key + 32 < m) ? 0.f : -1e9f;
                }
                a0 = __builtin_amdgcn_mfma_f32_32x32x16_bf16(kf0, qf[0], c0, 0, 0, 0);
                a1 = __builtin_amdgcn_mfma_f32_32x32x16_bf16(kf1, qf[0], c1, 0, 0, 0);
            }
        }
#pragma unroll
        for (int kd = 1; kd < 4; ++kd) {
            int co = (kd * 16 + hb * 8) * 2;
            bf16x8 kf0 = *(const bf16x8*)(kbp + ((rb0 + co) ^ sz0));
            bf16x8 kf1 = *(const bf16x8*)(kbp + ((rb1 + co) ^ sz0));
            a0 = __builtin_amdgcn_mfma_f32_32x32x16_bf16(kf0, qf[kd], a0, 0, 0, 0);
            a1 = __builtin_amdgcn_mfma_f32_32x32x16_bf16(kf1, qf[kd], a1, 0, 0, 0);
        }
        __builtin_amdgcn_s_setprio(0);
        st0 = a0; st1 = a1;
    };

    u32 w[2][8];    // packed P of the tile being finished (reused per phase)

    auto SM = [&]() {   // P = exp2(st) -> w, accumulate own-lane partial sum
        float rs0 = 0.f, rs1 = 0.f;
#pragma unroll
        for (int mm = 0; mm < 8; ++mm) {
            float p0 = __builtin_amdgcn_exp2f(st0[2 * mm]);
            float p1 = __builtin_amdgcn_exp2f(st0[2 * mm + 1]);
            rs0 += p0; rs1 += p1;
            u32 r;
            asm("v_cvt_pk_bf16_f32 %0, %1, %2" : "=v"(r) : "v"(p0), "v"(p1));
            w[0][mm] = r;
        }
#pragma unroll
        for (int mm = 0; mm < 8; ++mm) {
            float p0 = __builtin_amdgcn_exp2f(st1[2 * mm]);
            float p1 = __builtin_amdgcn_exp2f(st1[2 * mm + 1]);
            rs0 += p0; rs1 += p1;
            u32 r;
            asm("v_cvt_pk_bf16_f32 %0, %1, %2" : "=v"(r) : "v"(p0), "v"(p1));
            w[1][mm] = r;
        }
        lpart += rs0 + rs1;   // cross-half shfl deferred to epilogue
    };

    auto PV = [&](int sel) {   // O += P V from V slot sel
        const char* vbp = (const char*)vbuf + sel * (D_K * KVB * 2);
#pragma unroll
        for (int kbi = 0; kbi < 4; ++kbi) {
            int c = kbi >> 1, a2 = (kbi & 1) * 4;
            u32 x0 = w[c][a2 + 0], y0 = w[c][a2 + 2];
            u32 x1 = w[c][a2 + 1], y1 = w[c][a2 + 3];
            asm("v_permlane32_swap_b32 %0, %1" : "+v"(x0), "+v"(y0));
            asm("v_permlane32_swap_b32 %0, %1" : "+v"(x1), "+v"(y1));
            u32x4 av = {x0, x1, y0, y1};       // j01, j23, j45, j67
            bf16x8 pa = __builtin_bit_cast(bf16x8, av);
            __builtin_amdgcn_s_setprio(1);
#pragma unroll
            for (int dn = 0; dn < 2; ++dn) {
                int d = dn * 32 + ql;
                bf16x8 vf = *(const bf16x8*)(vbp +
                              ((d * 128 + (kbi * 16 + hb * 8) * 2) ^ vswz(d)));
                if (dn == 0)
                    o0 = __builtin_amdgcn_mfma_f32_32x32x16_bf16(pa, vf, o0, 0, 0, 0);
                else
                    o1 = __builtin_amdgcn_mfma_f32_32x32x16_bf16(pa, vf, o1, 0, 0, 0);
            }
            __builtin_amdgcn_s_setprio(0);
        }
    };

    // ---- prologue: stage K0..K3, V0..V1; drain; seed QK(0); barrier ----
    STAGE_K(0);
    STAGE_V(0);
    if (NTr > 1) { STAGE_K(1); STAGE_V(1); }
    if (NTr > 2) STAGE_K(2);
    if (NTr > 3) STAGE_K(3);
    __syncthreads();          // vmcnt(0) drain: all prologue tiles in LDS
    QK(0, 0, NTr == 1);
    __syncthreads();          // protect K slot0 (span 0 stages K5 -> slot 0)

    for (int u = 0; 2 * u < NTr; ++u) {
        const int t0 = 2 * u, t1 = 2 * u + 1;
        if (t0 + 4 < NTr) STAGE_K(t0 + 4);
        if (t0 + 5 < NTr) STAGE_K(t0 + 5);
        if (t0 + 2 < NTr) STAGE_V(t0 + 2);
        if (t0 + 3 < NTr) STAGE_V(t0 + 3);

        // ---- tile t0 ----
        SM();
        if (t0 + 1 < NTr) QK((t0 + 1) * KVB, (t0 + 1) % 5, t0 + 2 == NTr);
        PV(t0 & 3);

        // ---- tile t1 ----
        if (t1 < NTr) {
            SM();
            if (t1 + 1 < NTr) QK((t1 + 1) * KVB, (t1 + 1) % 5, t1 + 2 == NTr);
            PV(t1 & 3);
        }

        __syncthreads();   // span end: drains this span's stages; frees slots
    }

    // ---- epilogue: lrun = own + partner halves; out = o / lrun ----
    float lrun = lpart + __shfl_xor(lpart, 32, 64);
    float rl = 1.0f / lrun;
#pragma unroll
    for (int r = 0; r < 16; ++r) {
        int   cr  = (r & 3) + 8 * (r >> 2) + 4 * hb;
        float rlr = __shfl(rl, cr, 64);
        long  rowb = baseq + (long)(qrow0 + cr) * D_K;
        out[rowb + ql]      = o0[r] * rlr;
        out[rowb + 32 + ql] = o1[r] * rlr;
    }
}

// ---------------- fallback (no compaction) if ws too small ----------------
__global__ __launch_bounds__(256)
void attn_fwd_legacy(const float* __restrict__ q, const float* __restrict__ k,
                     const float* __restrict__ v, const int* __restrict__ mask,
                     float* __restrict__ out) {
    const int id      = blockIdx.x;
    const int logical = (id & 7) * 128 + (id >> 3);
    const int bh      = logical >> 4;
    const int qblk    = logical & 15;
    const int b       = bh >> 4;
    const int t       = threadIdx.x;
    const int lane    = t & 63;
    const int wq      = t >> 6;
    const int hb      = lane >> 5;
    const int ql      = lane & 31;

    __shared__ __align__(16) short kbuf[KVB * D_K];
    __shared__ __align__(16) short vtbuf[D_K * KVB];
    __shared__ float mbias[S_LEN];

    const float scale2 = 0.125f * 1.44269504f;
    const long  base   = (long)bh * S_LEN * D_K;
    const int   qrow0  = qblk * 128 + wq * 32;

    {
        const int* mb = mask + b * S_LEN;
        for (int i = t; i < S_LEN; i += 256)
            mbias[i] = mb[i] ? 0.f : -1.442695e9f;
    }

    bf16x8 qf[4];
    {
        const float* qp = q + base + (long)(qrow0 + ql) * D_K + hb * 8;
#pragma unroll
        for (int kd = 0; kd < 4; ++kd) qf[kd] = cvt8s(qp + kd * 16, 1.0f);
    }

    f32x16 o0, o1;
#pragma unroll
    for (int r = 0; r < 16; ++r) { o0[r] = 0.f; o1[r] = 0.f; }
    float mrun = -1e30f, lrun = 0.f;

    const int srow = t >> 3;
    const int scol = t & 7;
    float4 kr[2][2], vr[2][2];

    auto LOADT = [&](int kv0) {
#pragma unroll
        for (int u2 = 0; u2 < 2; ++u2) {
            int row = srow + u2 * 32;
            const float* kp = k + base + (long)(kv0 + row) * D_K + scol * 8;
            const float* vp = v + base + (long)(kv0 + row) * D_K + scol * 8;
            kr[u2][0] = *(const float4*)kp; kr[u2][1] = *(const float4*)(kp + 4);
            vr[u2][0] = *(const float4*)vp; vr[u2][1] = *(const float4*)(vp + 4);
        }
    };

    LOADT(0);

    for (int tt = 0; tt < S_LEN / KVB; ++tt) {
        const int kv0 = tt * KVB;
        __syncthreads();
#pragma unroll
        for (int u2 = 0; u2 < 2; ++u2) {
            int row = srow + u2 * 32;
            bf16x8 fk, fv;
#pragma unroll
            for (int j = 0; j < 4; ++j) {
                fk[j]     = f2bfs(((const float*)&kr[u2][0])[j]);
                fk[j + 4] = f2bfs(((const float*)&kr[u2][1])[j]);
                fv[j]     = f2bfs(((const float*)&vr[u2][0])[j]);
                fv[j + 4] = f2bfs(((const float*)&vr[u2][1])[j]);
            }
            int kbyte = (row * 128 + scol * 16) ^ ((row & 7) << 4);
            *(bf16x8*)((char*)kbuf + kbyte) = fk;
#pragma unroll
            for (int j = 0; j < 8; ++j) {
                int d = scol * 8 + j;
                *(short*)((char*)vtbuf + ((d * 128 + row * 2) ^ vswz(d))) = fv[j];
            }
        }
        if (tt + 1 < S_LEN / KVB) LOADT(kv0 + KVB);
        __syncthreads();

        f32x16 stl[2];
#pragma unroll
        for (int kb32 = 0; kb32 < 2; ++kb32) {
            f32x16 acc;
#pragma unroll
            for (int r = 0; r < 16; ++r) acc[r] = 0.f;
            int krow = kb32 * 32 + ql;
            int rb = krow * 128, sz = (krow & 7) << 4;
#pragma unroll
            for (int kd = 0; kd < 4; ++kd) {
                bf16x8 kf = *(const bf16x8*)((const char*)kbuf + ((rb + (kd * 16 + hb * 8) * 2) ^ sz));
                acc = __builtin_amdgcn_mfma_f32_32x32x16_bf16(kf, qf[kd], acc, 0, 0, 0);
            }
            stl[kb32] = acc;
        }
#pragma unroll
        for (int kb32 = 0; kb32 < 2; ++kb32)
#pragma unroll
            for (int r = 0; r < 16; ++r) {
                int key = kv0 + kb32 * 32 + (r & 3) + 8 * (r >> 2) + 4 * hb;
                stl[kb32][r] = fmaf(stl[kb32][r], scale2, mbias[key]);
            }

        float m8[8];
#pragma unroll
        for (int i = 0; i < 8; ++i)
            m8[i] = fmaxf(fmaxf(stl[0][i], stl[0][i + 8]),
                          fmaxf(stl[1][i], stl[1][i + 8]));
        float tmax = fmaxf(fmaxf(fmaxf(m8[0], m8[1]), fmaxf(m8[2], m8[3])),
                           fmaxf(fmaxf(m8[4], m8[5]), fmaxf(m8[6], m8[7])));
        tmax = fmaxf(tmax, __shfl_xor(tmax, 32, 64));

        if (__any(tmax > mrun + 10.0f)) {
            float mnew = fmaxf(mrun, tmax);
            float al   = __builtin_amdgcn_exp2f(mrun - mnew);
            mrun = mnew;
            lrun *= al;
#pragma unroll
            for (int r = 0; r < 16; ++r) {
                float ar = __shfl(al, (r & 3) + 8 * (r >> 2) + 4 * hb, 64);
                o0[r] *= ar; o1[r] *= ar;
            }
        }

        u32 w[2][8];
        float rs = 0.f;
#pragma unroll
        for (int kb32 = 0; kb32 < 2; ++kb32)
#pragma unroll
            for (int mm = 0; mm < 8; ++mm) {
                float p0 = __builtin_amdgcn_exp2f(stl[kb32][2 * mm]     - mrun);
                float p1 = __builtin_amdgcn_exp2f(stl[kb32][2 * mm + 1] - mrun);
                rs += p0 + p1;
                w[kb32][mm] = (u32)(unsigned short)f2bfs(p0) |
                              ((u32)(unsigned short)f2bfs(p1) << 16);
            }
        rs += __shfl_xor(rs, 32, 64);
        lrun += rs;

#pragma unroll
        for (int kbi = 0; kbi < 4; ++kbi) {
            int c = kbi >> 1, a2 = (kbi & 1) * 4;
            u32 x0 = w[c][a2 + 0], y0 = w[c][a2 + 2];
            u32 x1 = w[c][a2 + 1], y1 = w[c][a2 + 3];
            asm("v_permlane32_swap_b32 %0, %1" : "+v"(x0), "+v"(y0));
            asm("v_permlane32_swap_b32 %0, %1" : "+v"(x1), "+v"(y1));
            u32x4 av = {x0, x1, y0, y1};
            bf16x8 pa = __builtin_bit_cast(bf16x8, av);
#pragma unroll
            for (int dn = 0; dn < 2; ++dn) {
                int d = dn * 32 + ql;
                bf16x8 vf = *(const bf16x8*)((const char*)vtbuf +
                              ((d * 128 + (kbi * 16 + hb * 8) * 2) ^ vswz(d)));
                if (dn == 0)
                    o0 = __builtin_amdgcn_mfma_f32_32x32x16_bf16(pa, vf, o0, 0, 0, 0);
                else
                    o1 = __builtin_amdgcn_mfma_f32_32x32x16_bf16(pa, vf, o1, 0, 0, 0);
            }
        }
    }

    float rl = 1.0f / lrun;
#pragma unroll
    for (int r = 0; r < 16; ++r) {
        int   cr  = (r & 3) + 8 * (r >> 2) + 4 * hb;
        float rlr = __shfl(rl, cr, 64);
        long  rowb = base + (long)(qrow0 + cr) * D_K;
        out[rowb + ql]      = o0[r] * rlr;
        out[rowb + 32 + ql] = o1[r] * rlr;
    }
}

extern "C" void kernel_launch(void* const* d_in, const int* in_sizes, int n_in,
                              void* d_out, int out_size, void* d_ws, size_t ws_size,
                              hipStream_t stream) {
    const float* q    = (const float*)d_in[0];
    const float* k    = (const float*)d_in[1];
    const float* v    = (const float*)d_in[2];
    const int*   mask = (const int*)d_in[3];
    float*       out  = (float*)d_out;

    if (ws_size >= (size_t)WS_NEED) {
        short* kc  = (short*)d_ws;
        short* vt  = kc + (long)NBH * S_LEN * D_K;
        int*   cnt = (int*)(vt + (long)NBH * S_LEN * D_K);
        gather_cvt<<<dim3(NBH * (S_LEN / 64)), 256, 0, stream>>>(k, v, mask, 0, kc, vt, cnt);
        attn_fwd<<<dim3(NQB * NBH), 512, 0, stream>>>(q, kc, vt, cnt, out);
    } else {
        attn_fwd_legacy<<<dim3((S_LEN / 128) * NBH), 256, 0, stream>>>(q, k, v, mask, out);
    }
}